// Round 4
// baseline (333.299 us; speedup 1.0000x reference)
//
#include <hip/hip_runtime.h>
#include <stdint.h>

// B=2, T=2048, C=768, H=12, D=64. All inputs fp32; output fp32.
// Internally: f16 MFMA (16x16x32), fp32 accumulation.
// GEMMs: glds width=16 staging, XOR-swizzled LDS (round 3: 0 bank conflicts),
// double-buffered with ONE barrier per K-iteration (prefetch issued after the
// barrier so the barrier's vmcnt(0) drains loads that overlapped compute).

typedef __attribute__((ext_vector_type(8))) _Float16 half8;
typedef __attribute__((ext_vector_type(4))) float f32x4;

__device__ inline f32x4 mfma16(half8 a, half8 b, f32x4 c) {
    return __builtin_amdgcn_mfma_f32_16x16x32_f16(a, b, c, 0, 0, 0);
}

__device__ __forceinline__ void gld16(const _Float16* g, _Float16* lds) {
    __builtin_amdgcn_global_load_lds(
        (const __attribute__((address_space(1))) void*)(uintptr_t)g,
        (__attribute__((address_space(3))) void*)(uint32_t)(uintptr_t)lds,
        16, 0, 0);
}

// ---------------- weight repacks ----------------
__global__ __launch_bounds__(256) void repack_qkv(const float* __restrict__ wq,
                                                  const float* __restrict__ wk,
                                                  const float* __restrict__ wv,
                                                  _Float16* __restrict__ wt) {
    __shared__ float tile[32][33];
    int y = blockIdx.y;                 // sel*24 + h*2 + dt
    int sel = y / 24, rem = y % 24, h = rem >> 1, dt = rem & 1;
    const float* src = (sel == 0) ? wq : ((sel == 1) ? wk : wv);
    int c0 = blockIdx.x * 32, d0 = dt * 32;
    int tx = threadIdx.x & 31, ty = threadIdx.x >> 5;
#pragma unroll
    for (int i = 0; i < 4; i++) {
        int c = ty + i * 8;
        tile[c][tx] = src[((size_t)h * 768 + c0 + c) * 64 + d0 + tx];
    }
    __syncthreads();
#pragma unroll
    for (int i = 0; i < 4; i++) {
        int d = ty + i * 8;
        wt[((size_t)(sel * 768 + h * 64 + d0 + d)) * 768 + c0 + tx] = (_Float16)tile[tx][d];
    }
}

__global__ __launch_bounds__(256) void repack_t(const float* __restrict__ w,
                                                _Float16* __restrict__ wt, int K, int N) {
    __shared__ float tile[32][33];
    int n0 = blockIdx.x * 32, k0 = blockIdx.y * 32;
    int tx = threadIdx.x & 31, ty = threadIdx.x >> 5;
#pragma unroll
    for (int i = 0; i < 4; i++) {
        int k = ty + i * 8;
        tile[k][tx] = w[(size_t)(k0 + k) * N + n0 + tx];
    }
    __syncthreads();
#pragma unroll
    for (int i = 0; i < 4; i++) {
        int n = ty + i * 8;
        wt[(size_t)(n0 + n) * K + k0 + tx] = (_Float16)tile[tx][n];
    }
}

// ---------------- layernorm ----------------
__global__ __launch_bounds__(256) void ln_kernel(const float* __restrict__ x,
                                                 const float* __restrict__ g,
                                                 const float* __restrict__ bta,
                                                 _Float16* __restrict__ out) {
    int row = blockIdx.x;
    const float* xr = x + (size_t)row * 768;
    int tid = threadIdx.x;
    float v[3], s = 0.f, s2 = 0.f;
#pragma unroll
    for (int i = 0; i < 3; i++) { v[i] = xr[tid + i * 256]; s += v[i]; s2 += v[i] * v[i]; }
#pragma unroll
    for (int off = 32; off; off >>= 1) { s += __shfl_down(s, off, 64); s2 += __shfl_down(s2, off, 64); }
    __shared__ float red[8];
    int wave = tid >> 6, lane = tid & 63;
    if (lane == 0) { red[wave] = s; red[4 + wave] = s2; }
    __syncthreads();
    if (tid == 0) {
        float ts = red[0] + red[1] + red[2] + red[3];
        float ts2 = red[4] + red[5] + red[6] + red[7];
        float mu = ts * (1.f / 768.f);
        float var = ts2 * (1.f / 768.f) - mu * mu;
        red[0] = mu; red[1] = rsqrtf(var + 1e-5f);
    }
    __syncthreads();
    float mu = red[0], rstd = red[1];
#pragma unroll
    for (int i = 0; i < 3; i++) {
        int c = tid + i * 256;
        out[(size_t)row * 768 + c] = (_Float16)((v[i] - mu) * rstd * g[c] + bta[c]);
    }
}

// x2 = x + attnO/attnL; h2 = LN(x2); outInit = x2 + b_proj
__global__ __launch_bounds__(256) void addln_kernel(const float* __restrict__ x,
                                                    const float* __restrict__ Oacc,
                                                    const float* __restrict__ Lacc,
                                                    const float* __restrict__ g,
                                                    const float* __restrict__ bta,
                                                    const float* __restrict__ bproj,
                                                    float* __restrict__ x2,
                                                    _Float16* __restrict__ out,
                                                    float* __restrict__ outInit) {
    int row = blockIdx.x;               // b*2048 + t
    int b = row >> 11, t = row & 2047;
    const float* xr = x + (size_t)row * 768;
    int tid = threadIdx.x;
    float v[3], s = 0.f, s2 = 0.f;
#pragma unroll
    for (int i = 0; i < 3; i++) {
        int c = tid + i * 256;
        int h = c >> 6, d = c & 63;
        size_t bh = (size_t)(b * 12 + h);
        float o = Oacc[(bh * 2048 + t) * 64 + d] / Lacc[bh * 2048 + t];
        v[i] = xr[c] + o;
        x2[(size_t)row * 768 + c] = v[i];
        outInit[(size_t)row * 768 + c] = v[i] + bproj[c];
        s += v[i]; s2 += v[i] * v[i];
    }
#pragma unroll
    for (int off = 32; off; off >>= 1) { s += __shfl_down(s, off, 64); s2 += __shfl_down(s2, off, 64); }
    __shared__ float red[8];
    int wave = tid >> 6, lane = tid & 63;
    if (lane == 0) { red[wave] = s; red[4 + wave] = s2; }
    __syncthreads();
    if (tid == 0) {
        float ts = red[0] + red[1] + red[2] + red[3];
        float ts2 = red[4] + red[5] + red[6] + red[7];
        float mu = ts * (1.f / 768.f);
        float var = ts2 * (1.f / 768.f) - mu * mu;
        red[0] = mu; red[1] = rsqrtf(var + 1e-5f);
    }
    __syncthreads();
    float mu = red[0], rstd = red[1];
#pragma unroll
    for (int i = 0; i < 3; i++) {
        int c = tid + i * 256;
        out[(size_t)row * 768 + c] = (_Float16)((v[i] - mu) * rstd * g[c] + bta[c]);
    }
}

// ---------------- MFMA GEMM BMx128 tile, dbuf glds, 1 barrier/iter ----------------
// LDS: row stride 32 halfs, chunk swizzle c' = c ^ ((row>>1)&3) (0 conflicts, r3).
// MODE 0: scatter q(b,h,t,d)[*1/sqrt(768)], k(b,h,t,d), vt(b,h,d,t)  (N=2304)
// MODE 1: +bias, relu -> f16 out [M][N]
// MODE 2: split-K (gridDim.z), atomicAdd into outF (pre-initialized)
template <int MODE, int BM>
__global__ __launch_bounds__(256) void gemm_kernel(
    const _Float16* __restrict__ A, const _Float16* __restrict__ Bt, int N, int K,
    const float* __restrict__ bias, float* __restrict__ outF, _Float16* __restrict__ outH,
    _Float16* __restrict__ qb, _Float16* __restrict__ kb, _Float16* __restrict__ vtb) {
    constexpr int IM = BM / 32;                       // m-frags per wave
    __shared__ __align__(16) _Float16 As[2][BM * 32];
    __shared__ __align__(16) _Float16 Bs[2][128 * 32];
    const int tid = threadIdx.x;
    const int wave = tid >> 6, lane = tid & 63;
    const int m0 = blockIdx.y * BM, n0 = blockIdx.x * 128;
    const int wm = (wave >> 1) * (BM / 2), wn = (wave & 1) * 64;
    const int lr = lane & 15, lq = lane >> 4;
    const int sr = lane >> 2;                         // staging row within 16
    const int sc = (lane & 3) ^ ((lane >> 3) & 3);    // swizzled source chunk

    const int kChunk = K / gridDim.z;
    const int kbeg = blockIdx.z * kChunk;
    const int nIter = kChunk >> 5;

    auto stage = [&](int k0, int bsel) {
#pragma unroll
        for (int t = 0; t < BM / 64; ++t) {
            int row = wave * (BM / 4) + t * 16;
            gld16(&A[(size_t)(m0 + row + sr) * K + k0 + sc * 8], &As[bsel][row * 32]);
        }
#pragma unroll
        for (int t = 0; t < 2; ++t) {
            int row = wave * 32 + t * 16;
            gld16(&Bt[(size_t)(n0 + row + sr) * K + k0 + sc * 8], &Bs[bsel][row * 32]);
        }
    };

    f32x4 acc[IM][4] = {};
    stage(kbeg, 0);

    for (int it = 0; it < nIter; ++it) {
        __syncthreads();                 // drains prefetch of tile `it`
        if (it + 1 < nIter) stage(kbeg + (it + 1) * 32, (it + 1) & 1);
        const int bs = it & 1;
        half8 af[IM], bf[4];
        const int cs = (lq ^ ((lr >> 1) & 3)) * 8;
#pragma unroll
        for (int i = 0; i < IM; i++) af[i] = *(const half8*)&As[bs][(wm + i * 16 + lr) * 32 + cs];
#pragma unroll
        for (int j = 0; j < 4; j++) bf[j] = *(const half8*)&Bs[bs][(wn + j * 16 + lr) * 32 + cs];
#pragma unroll
        for (int i = 0; i < IM; i++)
#pragma unroll
            for (int j = 0; j < 4; j++)
                acc[i][j] = mfma16(af[i], bf[j], acc[i][j]);
    }

    const float qscale = 0.03608439182435161f;  // 1/sqrt(768)
#pragma unroll
    for (int i = 0; i < IM; i++) {
#pragma unroll
        for (int j = 0; j < 4; j++) {
#pragma unroll
            for (int r = 0; r < 4; r++) {
                int m = m0 + wm + i * 16 + lq * 4 + r;
                int n = n0 + wn + j * 16 + lr;
                float v = acc[i][j][r];
                if constexpr (MODE == 0) {
                    int b = m >> 11, t = m & 2047;
                    int sel = n / 768, nn = n % 768;
                    int h = nn >> 6, d = nn & 63;
                    size_t bh = (size_t)(b * 12 + h);
                    if (sel == 0)      qb[(bh * 2048 + t) * 64 + d] = (_Float16)(v * qscale);
                    else if (sel == 1) kb[(bh * 2048 + t) * 64 + d] = (_Float16)v;
                    else               vtb[(bh * 64 + d) * 2048 + t] = (_Float16)v;
                } else if constexpr (MODE == 1) {
                    v += bias[n];
                    v = v > 0.f ? v : 0.f;
                    outH[(size_t)m * N + n] = (_Float16)v;
                } else {
                    atomicAdd(&outF[(size_t)m * N + n], v);
                }
            }
        }
    }
}

// ---------------- flash attention (causal), KV-split with linear merge ----------------
__global__ __launch_bounds__(256) void attn_kernel(const _Float16* __restrict__ qb,
                                                   const _Float16* __restrict__ kb,
                                                   const _Float16* __restrict__ vtb,
                                                   float* __restrict__ Oacc,
                                                   float* __restrict__ Lacc) {
    int idx = blockIdx.x, qt = 0, s = 0, acc0 = 0;
    for (int q = 0; q < 32; ++q) {
        int nk = (q + 2) >> 1, ns = (nk + 3) >> 2;
        if (idx < acc0 + ns) { qt = q; s = idx - acc0; break; }
        acc0 += ns;
    }
    const int nk = (qt + 2) >> 1;
    const int t0 = s * 4;
    const int t1 = (t0 + 4 < nk) ? (t0 + 4) : nk;
    const int bh = blockIdx.y;
    const int q0 = qt * 64;

    __shared__ __align__(16) _Float16 Ks[128 * 64];
    __shared__ __align__(16) _Float16 Vs[64 * 128];
    __shared__ __align__(16) _Float16 Ps[4][16 * 136];
    const int tid = threadIdx.x, wave = tid >> 6, lane = tid & 63;
    const int lr = lane & 15, lq = lane >> 4;
    const _Float16* qbase = qb + (size_t)bh * 2048 * 64;
    const _Float16* kbase = kb + (size_t)bh * 2048 * 64;
    const _Float16* vbase = vtb + (size_t)bh * 64 * 2048;

    half8 qf[2];
#pragma unroll
    for (int kd2 = 0; kd2 < 2; kd2++)
        qf[kd2] = *(const half8*)&qbase[(size_t)(q0 + wave * 16 + lr) * 64 + kd2 * 32 + lq * 8];

    f32x4 O[4] = {};
    float lsum[4] = {0.f, 0.f, 0.f, 0.f};

    for (int it = t0; it < t1; ++it) {
        const int kv0 = it << 7;
        const bool needMask = (kv0 + 128 > q0);
#pragma unroll
        for (int u = 0; u < 4; ++u) {
            int tk = wave * 4 + u;
            gld16(&kbase[(size_t)(kv0 + tk * 8 + (lane >> 3)) * 64 +
                         (((lane & 7) ^ ((lane >> 3) & 7)) * 8)],
                  &Ks[tk * 8 * 64]);
        }
#pragma unroll
        for (int u = 0; u < 4; ++u) {
            int tv = wave * 4 + u;
            int vr = tv * 4 + (lane >> 4);
            gld16(&vbase[(size_t)vr * 2048 + kv0 + (((lane & 15) ^ (vr & 15)) * 8)],
                  &Vs[tv * 4 * 128]);
        }
        __syncthreads();

        f32x4 S[8] = {};
#pragma unroll
        for (int kd2 = 0; kd2 < 2; kd2++) {
#pragma unroll
            for (int nf = 0; nf < 8; nf++) {
                half8 bk = *(const half8*)&Ks[(nf * 16 + lr) * 64 +
                                              (((kd2 * 4 + lq) ^ (lr & 7)) * 8)];
                S[nf] = mfma16(qf[kd2], bk, S[nf]);
            }
        }

        const int qi_base = q0 + wave * 16 + lq * 4;
#pragma unroll
        for (int r = 0; r < 4; r++) {
            float a = 0.f;
#pragma unroll
            for (int nf = 0; nf < 8; nf++) {
                float p = __expf(S[nf][r]);
                if (needMask) {
                    int j = kv0 + nf * 16 + lr;
                    if (j > qi_base + r) p = 0.f;
                }
                a += p;
                Ps[wave][(lq * 4 + r) * 136 + nf * 16 + lr] = (_Float16)p;
            }
            lsum[r] += a;
        }

#pragma unroll
        for (int ks = 0; ks < 4; ks++) {
            half8 ap = *(const half8*)&Ps[wave][lr * 136 + ks * 32 + lq * 8];
#pragma unroll
            for (int df = 0; df < 4; df++) {
                half8 bv = *(const half8*)&Vs[(df * 16 + lr) * 128 +
                                              (((ks * 4 + lq) ^ lr) * 8)];
                O[df] = mfma16(ap, bv, O[df]);
            }
        }
        __syncthreads();
    }

#pragma unroll
    for (int r = 0; r < 4; r++) {
#pragma unroll
        for (int off = 1; off < 16; off <<= 1) lsum[r] += __shfl_xor(lsum[r], off, 64);
    }

#pragma unroll
    for (int df = 0; df < 4; df++) {
#pragma unroll
        for (int r = 0; r < 4; r++) {
            int t = q0 + wave * 16 + lq * 4 + r;
            int d = df * 16 + lr;
            atomicAdd(&Oacc[((size_t)bh * 2048 + t) * 64 + d], O[df][r]);
        }
    }
    if (lr == 0) {
#pragma unroll
        for (int r = 0; r < 4; r++) {
            int t = q0 + wave * 16 + lq * 4 + r;
            atomicAdd(&Lacc[(size_t)bh * 2048 + t], lsum[r]);
        }
    }
}

extern "C" void kernel_launch(void* const* d_in, const int* in_sizes, int n_in,
                              void* d_out, int out_size, void* d_ws, size_t ws_size,
                              hipStream_t stream) {
    (void)in_sizes; (void)n_in; (void)out_size; (void)ws_size;
    const float* x        = (const float*)d_in[0];
    const float* ln1_g    = (const float*)d_in[1];
    const float* ln1_b    = (const float*)d_in[2];
    const float* wq       = (const float*)d_in[3];
    const float* wk       = (const float*)d_in[4];
    const float* wv       = (const float*)d_in[5];
    const float* ln2_g    = (const float*)d_in[6];
    const float* ln2_b    = (const float*)d_in[7];
    const float* w_hidden = (const float*)d_in[8];
    const float* b_hidden = (const float*)d_in[9];
    const float* w_proj   = (const float*)d_in[10];
    const float* b_proj   = (const float*)d_in[11];
    float* out = (float*)d_out;

    uint8_t* p = (uint8_t*)d_ws;
    _Float16* h1   = (_Float16*)p; p += 4096ull * 768 * 2;
    _Float16* wqkv = (_Float16*)p; p += 2304ull * 768 * 2;
    _Float16* wh   = (_Float16*)p; p += 3072ull * 768 * 2;
    _Float16* wp   = (_Float16*)p; p += 768ull * 3072 * 2;
    _Float16* qb   = (_Float16*)p; p += 24ull * 2048 * 64 * 2;
    _Float16* kb   = (_Float16*)p; p += 24ull * 2048 * 64 * 2;
    _Float16* vtb  = (_Float16*)p; p += 24ull * 2048 * 64 * 2;
    float*    Oacc = (float*)p;    p += 24ull * 2048 * 64 * 4;
    float*    Lacc = (float*)p;    p += 24ull * 2048 * 4;
    float*    x2   = (float*)p;    p += 4096ull * 768 * 4;
    _Float16* h2   = (_Float16*)p; p += 4096ull * 768 * 2;
    _Float16* hid  = (_Float16*)p; p += 4096ull * 3072 * 2;

    hipMemsetAsync(Oacc, 0, (24ull * 2048 * 64 + 24ull * 2048) * 4, stream);

    repack_qkv<<<dim3(24, 72), 256, 0, stream>>>(wq, wk, wv, wqkv);
    repack_t<<<dim3(96, 24), 256, 0, stream>>>(w_hidden, wh, 768, 3072);
    repack_t<<<dim3(24, 96), 256, 0, stream>>>(w_proj, wp, 3072, 768);
    ln_kernel<<<4096, 256, 0, stream>>>(x, ln1_g, ln1_b, h1);
    gemm_kernel<0, 64><<<dim3(18, 64), 256, 0, stream>>>(h1, wqkv, 2304, 768,
        nullptr, nullptr, nullptr, qb, kb, vtb);
    attn_kernel<<<dim3(80, 24), 256, 0, stream>>>(qb, kb, vtb, Oacc, Lacc);
    addln_kernel<<<4096, 256, 0, stream>>>(x, Oacc, Lacc, ln2_g, ln2_b, b_proj, x2, h2, out);
    gemm_kernel<1, 64><<<dim3(24, 64), 256, 0, stream>>>(h2, wh, 3072, 768,
        b_hidden, nullptr, hid, nullptr, nullptr, nullptr);
    gemm_kernel<2, 64><<<dim3(6, 64, 8), 256, 0, stream>>>(hid, wp, 768, 3072,
        nullptr, out, nullptr, nullptr, nullptr, nullptr);
}

// Round 5
// 303.777 us; speedup vs baseline: 1.0972x; 1.0972x over previous
//
#include <hip/hip_runtime.h>
#include <stdint.h>

// B=2, T=2048, C=768, H=12, D=64. All inputs fp32; output fp32.
// Internally: f16 MFMA (16x16x32), fp32 accumulation.
// GEMMs: r3 structure (glds width=16, XOR swizzle, 0 bank conflicts) with
// BK=64: 32 MFMA + 16 ds_read_b128 per iteration between barriers (2x the
// MFMA-per-barrier of BK=32), 12 iterations for K=768.

typedef __attribute__((ext_vector_type(8))) _Float16 half8;
typedef __attribute__((ext_vector_type(4))) float f32x4;

__device__ inline f32x4 mfma16(half8 a, half8 b, f32x4 c) {
    return __builtin_amdgcn_mfma_f32_16x16x32_f16(a, b, c, 0, 0, 0);
}

__device__ __forceinline__ void gld16(const _Float16* g, _Float16* lds) {
    __builtin_amdgcn_global_load_lds(
        (const __attribute__((address_space(1))) void*)(uintptr_t)g,
        (__attribute__((address_space(3))) void*)(uint32_t)(uintptr_t)lds,
        16, 0, 0);
}

// ---------------- fused prep: LN1 + all three weight repacks ----------------
// blocks [0,4096): ln rows; [4096,5824): qkv repack; [5824,8128): wh; [8128,10432): wp
__global__ __launch_bounds__(256) void prep_kernel(
    const float* __restrict__ x, const float* __restrict__ g, const float* __restrict__ bta,
    _Float16* __restrict__ h1,
    const float* __restrict__ wq, const float* __restrict__ wk, const float* __restrict__ wv,
    _Float16* __restrict__ wqkv,
    const float* __restrict__ w_hidden, _Float16* __restrict__ wh,
    const float* __restrict__ w_proj, _Float16* __restrict__ wp) {
    __shared__ float tile[32][33];
    int bid = blockIdx.x;
    int tid = threadIdx.x;
    if (bid < 4096) {
        // ---- LN1 ----
        int row = bid;
        const float* xr = x + (size_t)row * 768;
        float v[3], s = 0.f, s2 = 0.f;
#pragma unroll
        for (int i = 0; i < 3; i++) { v[i] = xr[tid + i * 256]; s += v[i]; s2 += v[i] * v[i]; }
#pragma unroll
        for (int off = 32; off; off >>= 1) { s += __shfl_down(s, off, 64); s2 += __shfl_down(s2, off, 64); }
        float* red = &tile[0][0];
        int wave = tid >> 6, lane = tid & 63;
        if (lane == 0) { red[wave] = s; red[4 + wave] = s2; }
        __syncthreads();
        if (tid == 0) {
            float ts = red[0] + red[1] + red[2] + red[3];
            float ts2 = red[4] + red[5] + red[6] + red[7];
            float mu = ts * (1.f / 768.f);
            float var = ts2 * (1.f / 768.f) - mu * mu;
            red[0] = mu; red[1] = rsqrtf(var + 1e-5f);
        }
        __syncthreads();
        float mu = red[0], rstd = red[1];
#pragma unroll
        for (int i = 0; i < 3; i++) {
            int c = tid + i * 256;
            h1[(size_t)row * 768 + c] = (_Float16)((v[i] - mu) * rstd * g[c] + bta[c]);
        }
        return;
    }
    int tx = tid & 31, ty = tid >> 5;
    if (bid < 5824) {
        // ---- qkv repack: idx = (bx 24)*(y 72) ----
        int idx = bid - 4096;
        int y = idx / 24, bx = idx % 24;
        int sel = y / 24, rem = y % 24, h = rem >> 1, dt = rem & 1;
        const float* src = (sel == 0) ? wq : ((sel == 1) ? wk : wv);
        int c0 = bx * 32, d0 = dt * 32;
#pragma unroll
        for (int i = 0; i < 4; i++) {
            int c = ty + i * 8;
            tile[c][tx] = src[((size_t)h * 768 + c0 + c) * 64 + d0 + tx];
        }
        __syncthreads();
#pragma unroll
        for (int i = 0; i < 4; i++) {
            int d = ty + i * 8;
            wqkv[((size_t)(sel * 768 + h * 64 + d0 + d)) * 768 + c0 + tx] = (_Float16)tile[tx][d];
        }
        return;
    }
    const float* w; _Float16* wt; int K, N, idx;
    if (bid < 8128) { idx = bid - 5824; w = w_hidden; wt = wh; K = 768; N = 3072; }
    else            { idx = bid - 8128; w = w_proj;   wt = wp; K = 3072; N = 768; }
    int nb = N / 32;
    int n0 = (idx % nb) * 32, k0 = (idx / nb) * 32;
#pragma unroll
    for (int i = 0; i < 4; i++) {
        int k = ty + i * 8;
        tile[k][tx] = w[(size_t)(k0 + k) * N + n0 + tx];
    }
    __syncthreads();
#pragma unroll
    for (int i = 0; i < 4; i++) {
        int n = ty + i * 8;
        wt[(size_t)(n0 + n) * K + k0 + tx] = (_Float16)tile[tx][n];
    }
}

// x2 = x + attnO/attnL; h2 = LN(x2); outInit = x2 + b_proj
__global__ __launch_bounds__(256) void addln_kernel(const float* __restrict__ x,
                                                    const float* __restrict__ Oacc,
                                                    const float* __restrict__ Lacc,
                                                    const float* __restrict__ g,
                                                    const float* __restrict__ bta,
                                                    const float* __restrict__ bproj,
                                                    float* __restrict__ x2,
                                                    _Float16* __restrict__ out,
                                                    float* __restrict__ outInit) {
    int row = blockIdx.x;               // b*2048 + t
    int b = row >> 11, t = row & 2047;
    const float* xr = x + (size_t)row * 768;
    int tid = threadIdx.x;
    float v[3], s = 0.f, s2 = 0.f;
#pragma unroll
    for (int i = 0; i < 3; i++) {
        int c = tid + i * 256;
        int h = c >> 6, d = c & 63;
        size_t bh = (size_t)(b * 12 + h);
        float o = Oacc[(bh * 2048 + t) * 64 + d] / Lacc[bh * 2048 + t];
        v[i] = xr[c] + o;
        x2[(size_t)row * 768 + c] = v[i];
        outInit[(size_t)row * 768 + c] = v[i] + bproj[c];
        s += v[i]; s2 += v[i] * v[i];
    }
#pragma unroll
    for (int off = 32; off; off >>= 1) { s += __shfl_down(s, off, 64); s2 += __shfl_down(s2, off, 64); }
    __shared__ float red[8];
    int wave = tid >> 6, lane = tid & 63;
    if (lane == 0) { red[wave] = s; red[4 + wave] = s2; }
    __syncthreads();
    if (tid == 0) {
        float ts = red[0] + red[1] + red[2] + red[3];
        float ts2 = red[4] + red[5] + red[6] + red[7];
        float mu = ts * (1.f / 768.f);
        float var = ts2 * (1.f / 768.f) - mu * mu;
        red[0] = mu; red[1] = rsqrtf(var + 1e-5f);
    }
    __syncthreads();
    float mu = red[0], rstd = red[1];
#pragma unroll
    for (int i = 0; i < 3; i++) {
        int c = tid + i * 256;
        out[(size_t)row * 768 + c] = (_Float16)((v[i] - mu) * rstd * g[c] + bta[c]);
    }
}

// ---------------- MFMA GEMM 128x128 tile, BK=64, glds staging ----------------
// LDS: row stride 64 halfs = 8 chunks of 16B; phys chunk = logical ^ (row&7).
// Frag-read bank check: each 8-lane subgroup reads a full permutation of the
// 8 chunks -> conflict-free (same criterion as r3's measured 0).
// MODE 0: scatter q(b,h,t,d)[*1/sqrt(768)], k(b,h,t,d), vt(b,h,d,t)  (N=2304)
// MODE 1: +bias, relu -> f16 out [M][N]
// MODE 2: split-K (gridDim.z), atomicAdd into outF (pre-initialized)
template <int MODE>
__global__ __launch_bounds__(256) void gemm_kernel(
    const _Float16* __restrict__ A, const _Float16* __restrict__ Bt, int N, int K,
    const float* __restrict__ bias, float* __restrict__ outF, _Float16* __restrict__ outH,
    _Float16* __restrict__ qb, _Float16* __restrict__ kb, _Float16* __restrict__ vtb) {
    __shared__ __align__(16) _Float16 As[128 * 64];
    __shared__ __align__(16) _Float16 Bs[128 * 64];
    const int tid = threadIdx.x;
    const int wave = tid >> 6, lane = tid & 63;
    const int m0 = blockIdx.y * 128, n0 = blockIdx.x * 128;
    const int wm = (wave >> 1) * 64, wn = (wave & 1) * 64;
    const int lr = lane & 15, lq = lane >> 4;
    const int sr = lane >> 3;                       // staging row within 8
    const int sc = (lane & 7) ^ sr;                 // swizzled logical chunk

    const int kChunk = K / gridDim.z;
    const int kbeg = blockIdx.z * kChunk;

    f32x4 acc[4][4] = {};

    for (int k0 = kbeg; k0 < kbeg + kChunk; k0 += 64) {
        // stage A,B: per wave 4+4 glds (8 rows x 128B each)
#pragma unroll
        for (int t = 0; t < 4; ++t) {
            int row = wave * 32 + t * 8;
            gld16(&A[(size_t)(m0 + row + sr) * K + k0 + sc * 8], &As[row * 64]);
            gld16(&Bt[(size_t)(n0 + row + sr) * K + k0 + sc * 8], &Bs[row * 64]);
        }
        __syncthreads();
#pragma unroll
        for (int ks = 0; ks < 2; ++ks) {
            half8 af[4], bf[4];
#pragma unroll
            for (int i = 0; i < 4; i++)
                af[i] = *(const half8*)&As[(wm + i * 16 + lr) * 64 + (((ks * 4 + lq) ^ (lr & 7)) * 8)];
#pragma unroll
            for (int j = 0; j < 4; j++)
                bf[j] = *(const half8*)&Bs[(wn + j * 16 + lr) * 64 + (((ks * 4 + lq) ^ (lr & 7)) * 8)];
#pragma unroll
            for (int i = 0; i < 4; i++)
#pragma unroll
                for (int j = 0; j < 4; j++)
                    acc[i][j] = mfma16(af[i], bf[j], acc[i][j]);
        }
        __syncthreads();
    }

    const float qscale = 0.03608439182435161f;  // 1/sqrt(768)
#pragma unroll
    for (int i = 0; i < 4; i++) {
#pragma unroll
        for (int j = 0; j < 4; j++) {
#pragma unroll
            for (int r = 0; r < 4; r++) {
                int m = m0 + wm + i * 16 + lq * 4 + r;
                int n = n0 + wn + j * 16 + lr;
                float v = acc[i][j][r];
                if constexpr (MODE == 0) {
                    int b = m >> 11, t = m & 2047;
                    int sel = n / 768, nn = n % 768;
                    int h = nn >> 6, d = nn & 63;
                    size_t bh = (size_t)(b * 12 + h);
                    if (sel == 0)      qb[(bh * 2048 + t) * 64 + d] = (_Float16)(v * qscale);
                    else if (sel == 1) kb[(bh * 2048 + t) * 64 + d] = (_Float16)v;
                    else               vtb[(bh * 64 + d) * 2048 + t] = (_Float16)v;
                } else if constexpr (MODE == 1) {
                    v += bias[n];
                    v = v > 0.f ? v : 0.f;
                    outH[(size_t)m * N + n] = (_Float16)v;
                } else {
                    atomicAdd(&outF[(size_t)m * N + n], v);
                }
            }
        }
    }
}

// ---------------- flash attention (causal), KV-split with linear merge ----------------
__global__ __launch_bounds__(256) void attn_kernel(const _Float16* __restrict__ qb,
                                                   const _Float16* __restrict__ kb,
                                                   const _Float16* __restrict__ vtb,
                                                   float* __restrict__ Oacc,
                                                   float* __restrict__ Lacc) {
    int idx = blockIdx.x, qt = 0, s = 0, acc0 = 0;
    for (int q = 0; q < 32; ++q) {
        int nk = (q + 2) >> 1, ns = (nk + 3) >> 2;
        if (idx < acc0 + ns) { qt = q; s = idx - acc0; break; }
        acc0 += ns;
    }
    const int nk = (qt + 2) >> 1;
    const int t0 = s * 4;
    const int t1 = (t0 + 4 < nk) ? (t0 + 4) : nk;
    const int bh = blockIdx.y;
    const int q0 = qt * 64;

    __shared__ __align__(16) _Float16 Ks[128 * 64];
    __shared__ __align__(16) _Float16 Vs[64 * 128];
    __shared__ __align__(16) _Float16 Ps[4][16 * 136];
    const int tid = threadIdx.x, wave = tid >> 6, lane = tid & 63;
    const int lr = lane & 15, lq = lane >> 4;
    const _Float16* qbase = qb + (size_t)bh * 2048 * 64;
    const _Float16* kbase = kb + (size_t)bh * 2048 * 64;
    const _Float16* vbase = vtb + (size_t)bh * 64 * 2048;

    half8 qf[2];
#pragma unroll
    for (int kd2 = 0; kd2 < 2; kd2++)
        qf[kd2] = *(const half8*)&qbase[(size_t)(q0 + wave * 16 + lr) * 64 + kd2 * 32 + lq * 8];

    f32x4 O[4] = {};
    float lsum[4] = {0.f, 0.f, 0.f, 0.f};

    for (int it = t0; it < t1; ++it) {
        const int kv0 = it << 7;
        const bool needMask = (kv0 + 128 > q0);
#pragma unroll
        for (int u = 0; u < 4; ++u) {
            int tk = wave * 4 + u;
            gld16(&kbase[(size_t)(kv0 + tk * 8 + (lane >> 3)) * 64 +
                         (((lane & 7) ^ ((lane >> 3) & 7)) * 8)],
                  &Ks[tk * 8 * 64]);
        }
#pragma unroll
        for (int u = 0; u < 4; ++u) {
            int tv = wave * 4 + u;
            int vr = tv * 4 + (lane >> 4);
            gld16(&vbase[(size_t)vr * 2048 + kv0 + (((lane & 15) ^ (vr & 15)) * 8)],
                  &Vs[tv * 4 * 128]);
        }
        __syncthreads();

        f32x4 S[8] = {};
#pragma unroll
        for (int kd2 = 0; kd2 < 2; kd2++) {
#pragma unroll
            for (int nf = 0; nf < 8; nf++) {
                half8 bk = *(const half8*)&Ks[(nf * 16 + lr) * 64 +
                                              (((kd2 * 4 + lq) ^ (lr & 7)) * 8)];
                S[nf] = mfma16(qf[kd2], bk, S[nf]);
            }
        }

        const int qi_base = q0 + wave * 16 + lq * 4;
#pragma unroll
        for (int r = 0; r < 4; r++) {
            float a = 0.f;
#pragma unroll
            for (int nf = 0; nf < 8; nf++) {
                float p = __expf(S[nf][r]);
                if (needMask) {
                    int j = kv0 + nf * 16 + lr;
                    if (j > qi_base + r) p = 0.f;
                }
                a += p;
                Ps[wave][(lq * 4 + r) * 136 + nf * 16 + lr] = (_Float16)p;
            }
            lsum[r] += a;
        }

#pragma unroll
        for (int ks = 0; ks < 4; ks++) {
            half8 ap = *(const half8*)&Ps[wave][lr * 136 + ks * 32 + lq * 8];
#pragma unroll
            for (int df = 0; df < 4; df++) {
                half8 bv = *(const half8*)&Vs[(df * 16 + lr) * 128 +
                                              (((ks * 4 + lq) ^ lr) * 8)];
                O[df] = mfma16(ap, bv, O[df]);
            }
        }
        __syncthreads();
    }

#pragma unroll
    for (int r = 0; r < 4; r++) {
#pragma unroll
        for (int off = 1; off < 16; off <<= 1) lsum[r] += __shfl_xor(lsum[r], off, 64);
    }

#pragma unroll
    for (int df = 0; df < 4; df++) {
#pragma unroll
        for (int r = 0; r < 4; r++) {
            int t = q0 + wave * 16 + lq * 4 + r;
            int d = df * 16 + lr;
            atomicAdd(&Oacc[((size_t)bh * 2048 + t) * 64 + d], O[df][r]);
        }
    }
    if (lr == 0) {
#pragma unroll
        for (int r = 0; r < 4; r++) {
            int t = q0 + wave * 16 + lq * 4 + r;
            atomicAdd(&Lacc[(size_t)bh * 2048 + t], lsum[r]);
        }
    }
}

extern "C" void kernel_launch(void* const* d_in, const int* in_sizes, int n_in,
                              void* d_out, int out_size, void* d_ws, size_t ws_size,
                              hipStream_t stream) {
    (void)in_sizes; (void)n_in; (void)out_size; (void)ws_size;
    const float* x        = (const float*)d_in[0];
    const float* ln1_g    = (const float*)d_in[1];
    const float* ln1_b    = (const float*)d_in[2];
    const float* wq       = (const float*)d_in[3];
    const float* wk       = (const float*)d_in[4];
    const float* wv       = (const float*)d_in[5];
    const float* ln2_g    = (const float*)d_in[6];
    const float* ln2_b    = (const float*)d_in[7];
    const float* w_hidden = (const float*)d_in[8];
    const float* b_hidden = (const float*)d_in[9];
    const float* w_proj   = (const float*)d_in[10];
    const float* b_proj   = (const float*)d_in[11];
    float* out = (float*)d_out;

    uint8_t* p = (uint8_t*)d_ws;
    _Float16* h1   = (_Float16*)p; p += 4096ull * 768 * 2;
    _Float16* wqkv = (_Float16*)p; p += 2304ull * 768 * 2;
    _Float16* wh   = (_Float16*)p; p += 3072ull * 768 * 2;
    _Float16* wp   = (_Float16*)p; p += 768ull * 3072 * 2;
    _Float16* qb   = (_Float16*)p; p += 24ull * 2048 * 64 * 2;
    _Float16* kb   = (_Float16*)p; p += 24ull * 2048 * 64 * 2;
    _Float16* vtb  = (_Float16*)p; p += 24ull * 2048 * 64 * 2;
    float*    Oacc = (float*)p;    p += 24ull * 2048 * 64 * 4;
    float*    Lacc = (float*)p;    p += 24ull * 2048 * 4;
    float*    x2   = (float*)p;    p += 4096ull * 768 * 4;
    _Float16* h2   = (_Float16*)p; p += 4096ull * 768 * 2;
    _Float16* hid  = (_Float16*)p; p += 4096ull * 3072 * 2;

    hipMemsetAsync(Oacc, 0, (24ull * 2048 * 64 + 24ull * 2048) * 4, stream);

    prep_kernel<<<10432, 256, 0, stream>>>(x, ln1_g, ln1_b, h1,
        wq, wk, wv, wqkv, w_hidden, wh, w_proj, wp);
    gemm_kernel<0><<<dim3(18, 32), 256, 0, stream>>>(h1, wqkv, 2304, 768,
        nullptr, nullptr, nullptr, qb, kb, vtb);
    attn_kernel<<<dim3(80, 24), 256, 0, stream>>>(qb, kb, vtb, Oacc, Lacc);
    addln_kernel<<<4096, 256, 0, stream>>>(x, Oacc, Lacc, ln2_g, ln2_b, b_proj, x2, h2, out);
    gemm_kernel<1><<<dim3(24, 32), 256, 0, stream>>>(h2, wh, 3072, 768,
        b_hidden, nullptr, hid, nullptr, nullptr, nullptr);
    gemm_kernel<2><<<dim3(6, 32, 4), 256, 0, stream>>>(hid, wp, 768, 3072,
        nullptr, out, nullptr, nullptr, nullptr, nullptr);
}